// Round 8
// baseline (1283.773 us; speedup 1.0000x reference)
//
#include <hip/hip_runtime.h>
#include <hip/hip_bf16.h>
#include <hip/hip_fp16.h>

#define N_NODES 100000
#define N_EDGES 3200000
#define F_IN    128
#define F_H     64

#define NBUCK 512
#define NPB   196            // ceil(N_NODES / NBUCK); buckets 510/511 short/empty
#define SRC_BITS 17          // N_NODES < 2^17; pack = (dstLocal<<17)|src  (25 bits)
#define SB    196            // src window bins: src>>9 in [0,196)

// ---------------------------------------------------------------------------
// Bucket-level histogram: 512 bins, LDS-aggregated
// ---------------------------------------------------------------------------
#define BH_T 256
#define BH_C 16384           // edges per block -> 196 blocks
__global__ __launch_bounds__(BH_T) void k_bhist(const int* __restrict__ dst,
                                                int* __restrict__ bcount) {
    __shared__ int lc[NBUCK];
    int t = threadIdx.x;
    lc[t] = 0; lc[t + 256] = 0;
    __syncthreads();
    long long e0 = (long long)blockIdx.x * BH_C;
    long long e1 = e0 + BH_C; if (e1 > N_EDGES) e1 = N_EDGES;
    for (long long e = e0 + t; e < e1; e += BH_T)
        atomicAdd(&lc[dst[e] / NPB], 1);
    __syncthreads();
    int c0 = lc[t], c1 = lc[t + 256];
    if (c0) atomicAdd(&bcount[t], c0);
    if (c1) atomicAdd(&bcount[t + 256], c1);
}

// ---------------------------------------------------------------------------
// Scan of 512 bucket counts -> bucket bases + partA cursors
// ---------------------------------------------------------------------------
__global__ __launch_bounds__(NBUCK) void k_bscan(const int* __restrict__ bcount,
                                                 int* __restrict__ bbase,
                                                 int* __restrict__ bcur) {
    __shared__ int s[NBUCK];
    int t = threadIdx.x;
    int c = bcount[t];
    s[t] = c;
    __syncthreads();
    for (int off = 1; off < NBUCK; off <<= 1) {
        int v = (t >= off) ? s[t - off] : 0;
        __syncthreads();
        s[t] += v;
        __syncthreads();
    }
    int ex = s[t] - c;
    bbase[t] = ex;
    bcur[t]  = ex;
    if (t == NBUCK - 1) bbase[NBUCK] = s[t];   // = N_EDGES
}

// ---------------------------------------------------------------------------
// wc2 = W2^T Wc (64-vector), c0 = Wc.b2 + bc  — collapses layer2+head
// ---------------------------------------------------------------------------
__global__ __launch_bounds__(64) void k_wc2(const float* __restrict__ W2,
                                            const float* __restrict__ Wc,
                                            const float* __restrict__ b2,
                                            const float* __restrict__ bc,
                                            float* __restrict__ wc2,
                                            float* __restrict__ c0) {
    int k = threadIdx.x;
    float s = 0.0f;
#pragma unroll 8
    for (int f = 0; f < F_H; f++) s += Wc[f] * W2[f * F_H + k];
    wc2[k] = s;
    float p = Wc[k] * b2[k];
#pragma unroll
    for (int off = 32; off > 0; off >>= 1) p += __shfl_xor(p, off, 64);
    if (k == 0) c0[0] = p + bc[0];
}

// ---------------------------------------------------------------------------
// Pass A: partition edges into NBUCK dst-range buckets; emit packed
// (dstLocal<<17)|src words (LDS-staged, coalesced out)
// ---------------------------------------------------------------------------
#define PA_T   256
#define PA_C   4096
#define PA_PER (PA_C / PA_T)   // 16
__global__ __launch_bounds__(PA_T) void k_partA(const int* __restrict__ src,
                                                const int* __restrict__ dst,
                                                int* __restrict__ bucket_cursor,
                                                int* __restrict__ packT) {
    __shared__ int lcount[NBUCK];
    __shared__ int lstart[NBUCK];
    __shared__ int loffs[NBUCK];
    __shared__ int lbase[NBUCK];
    __shared__ int s_pack[PA_C];
    __shared__ short s_bkt[PA_C];
    __shared__ int ltot;
    int t = threadIdx.x;
    long long e0 = (long long)blockIdx.x * PA_C;
    lcount[t] = 0; lcount[t + 256] = 0;
    __syncthreads();
    int ep[PA_PER];
    short eb[PA_PER];
#pragma unroll
    for (int i = 0; i < PA_PER; i++) {
        long long e = e0 + i * PA_T + t;
        if (e < N_EDGES) {
            int es = src[e], ed = dst[e];
            int b = ed / NPB;
            eb[i] = (short)b;
            ep[i] = ((ed - b * NPB) << SRC_BITS) | es;
            atomicAdd(&lcount[b], 1);
        } else eb[i] = -1;
    }
    __syncthreads();
    // exclusive scan of lcount (512) by wave 0: 8 serial/lane + shfl scan
    if (t < 64) {
        int base = t * 8;
        int c[8]; int ssum = 0;
#pragma unroll
        for (int j = 0; j < 8; j++) { c[j] = lcount[base + j]; ssum += c[j]; }
        int sc = ssum;
#pragma unroll
        for (int off = 1; off < 64; off <<= 1) {
            int v = __shfl_up(sc, off, 64);
            if (t >= off) sc += v;
        }
        int ex = sc - ssum;
#pragma unroll
        for (int j = 0; j < 8; j++) { lstart[base + j] = ex; ex += c[j]; }
        if (t == 63) ltot = ex;
    }
    __syncthreads();
    {
        int b0 = t, b1 = t + 256;
        loffs[b0] = lstart[b0];
        loffs[b1] = lstart[b1];
        int c0 = lcount[b0], c1 = lcount[b1];
        lbase[b0] = c0 ? atomicAdd(&bucket_cursor[b0], c0) : 0;
        lbase[b1] = c1 ? atomicAdd(&bucket_cursor[b1], c1) : 0;
    }
    __syncthreads();
#pragma unroll
    for (int i = 0; i < PA_PER; i++) {
        if (eb[i] >= 0) {
            int idx = atomicAdd(&loffs[eb[i]], 1);
            s_pack[idx] = ep[i];
            s_bkt[idx] = eb[i];
        }
    }
    __syncthreads();
    int tot = ltot;
    for (int i = t; i < tot; i += PA_T) {
        int b = s_bkt[i];
        int addr = lbase[b] + (i - lstart[b]);
        packT[addr] = s_pack[i];
    }
}

// ---------------------------------------------------------------------------
// Pass B: per-bucket counting sort by SRC-window (src>>9) -> packS segment,
// plus derives dinv[node] from the dstLocal histogram.
// Sortedness is a locality optimization only -> overflow fallback = raw copy.
// ---------------------------------------------------------------------------
#define PB_T   512
#define PB_CAP 8192
__global__ __launch_bounds__(PB_T) void k_partB(const int* __restrict__ bbase,
                                                const int* __restrict__ packT,
                                                float* __restrict__ dinv,
                                                int* __restrict__ packS) {
    __shared__ int lhd[NPB];     // dstLocal degree histogram
    __shared__ int lhs[SB];      // src-window histogram
    __shared__ int lcur[SB];
    __shared__ int s_out[PB_CAP];
    int b = blockIdx.x;
    int node0 = b * NPB;
    int nloc = N_NODES - node0; if (nloc > NPB) nloc = NPB; if (nloc < 0) nloc = 0;
    int beg = bbase[b], end = bbase[b + 1], len = end - beg;
    int t = threadIdx.x;
    const int SMASK = (1 << SRC_BITS) - 1;

    for (int i = t; i < NPB; i += PB_T) lhd[i] = 0;
    for (int i = t; i < SB; i += PB_T) lhs[i] = 0;
    __syncthreads();
    for (int i = t; i < len; i += PB_T) {
        int pk = packT[beg + i];
        atomicAdd(&lhd[pk >> SRC_BITS], 1);
        atomicAdd(&lhs[(pk & SMASK) >> 9], 1);
    }
    __syncthreads();
    for (int i = t; i < nloc; i += PB_T)
        dinv[node0 + i] = rsqrtf((float)(lhd[i] + 1));
    // exclusive scan of 196 src-window counters by wave 0: 4/lane + shfl
    if (t < 64) {
        int base = t * 4;
        int c[4]; int ssum = 0;
#pragma unroll
        for (int j = 0; j < 4; j++) {
            int idx = base + j;
            c[j] = (idx < SB) ? lhs[idx] : 0;
            ssum += c[j];
        }
        int sc = ssum;
#pragma unroll
        for (int off = 1; off < 64; off <<= 1) {
            int v = __shfl_up(sc, off, 64);
            if (t >= off) sc += v;
        }
        int ex = sc - ssum;
#pragma unroll
        for (int j = 0; j < 4; j++) {
            int idx = base + j;
            if (idx < SB) lcur[idx] = ex;
            ex += c[j];
        }
    }
    __syncthreads();
    if (len <= PB_CAP) {
        for (int i = t; i < len; i += PB_T) {
            int pk = packT[beg + i];
            int idx = atomicAdd(&lcur[(pk & SMASK) >> 9], 1);
            s_out[idx] = pk;
        }
        __syncthreads();
        for (int i = t; i < len; i += PB_T)
            packS[beg + i] = s_out[i];
    } else {    // statistically never (~24 sigma): unsorted copy, still correct
        for (int i = t; i < len; i += PB_T)
            packS[beg + i] = packT[beg + i];
    }
}

// ---------------------------------------------------------------------------
// Layer-1 GEMM: hs16 = fp16( (x @ W1^T) * dinv )   (unchanged from R5)
// ---------------------------------------------------------------------------
#define GT   256
#define NTB  128     // nodes per block
#define KT   64      // k-tile (2 passes for F_IN=128)
#define WTS  68      // wT stride (words)

__global__ __launch_bounds__(GT) void k_gemm1(const float* __restrict__ x,
                                              const float* __restrict__ W1,
                                              const float* __restrict__ dinv,
                                              __half* __restrict__ hs) {
    __shared__ float wT[KT * WTS];     // 17.4 KB
    __shared__ float xT[KT * NTB];     // 32 KB
    int t = threadIdx.x;
    int node0 = blockIdx.x * NTB;
    int lane = t & 63, wv = t >> 6;
    int fi = lane & 15, ni = lane >> 4;
    int n0 = wv * 32 + ni * 8;

    float acc[4][8];
#pragma unroll
    for (int r = 0; r < 4; r++)
#pragma unroll
        for (int c = 0; c < 8; c++) acc[r][c] = 0.0f;

    for (int p = 0; p < 2; p++) {
        int k0 = p * KT;
        if (p) __syncthreads();
        {
            int f = t & 63, kq = t >> 6;
            const float4* wp = (const float4*)&W1[(size_t)f * F_IN + k0 + kq * 16];
#pragma unroll
            for (int j = 0; j < 4; j++) {
                float4 v = wp[j];
                int kl = kq * 16 + 4 * j;
                wT[(kl + 0) * WTS + f] = v.x;
                wT[(kl + 1) * WTS + f] = v.y;
                wT[(kl + 2) * WTS + f] = v.z;
                wT[(kl + 3) * WTS + f] = v.w;
            }
        }
        {
            int n = t & 127, half = t >> 7;
            int node = node0 + n;
#pragma unroll
            for (int j = 0; j < 8; j++) {
                int ku = half * 8 + j;
                float4 v = make_float4(0.f, 0.f, 0.f, 0.f);
                if (node < N_NODES)
                    v = *(const float4*)&x[(size_t)node * F_IN + k0 + 4 * ku];
                int kl = 4 * ku;
                xT[(kl + 0) * NTB + n] = v.x;
                xT[(kl + 1) * NTB + n] = v.y;
                xT[(kl + 2) * NTB + n] = v.z;
                xT[(kl + 3) * NTB + n] = v.w;
            }
        }
        __syncthreads();
#pragma unroll 8
        for (int k = 0; k < KT; k++) {
            float4 wf = *(const float4*)&wT[k * WTS + fi * 4];
            float4 xa = *(const float4*)&xT[k * NTB + n0];
            float4 xb = *(const float4*)&xT[k * NTB + n0 + 4];
            float wr[4] = {wf.x, wf.y, wf.z, wf.w};
            float xv[8] = {xa.x, xa.y, xa.z, xa.w, xb.x, xb.y, xb.z, xb.w};
#pragma unroll
            for (int r = 0; r < 4; r++)
#pragma unroll
                for (int c = 0; c < 8; c++) acc[r][c] += wr[r] * xv[c];
        }
    }
#pragma unroll
    for (int c = 0; c < 8; c++) {
        int node = node0 + n0 + c;
        if (node < N_NODES) {
            float dv = dinv[node];
            __half2 h0 = __floats2half2_rn(acc[0][c] * dv, acc[1][c] * dv);
            __half2 h1 = __floats2half2_rn(acc[2][c] * dv, acc[3][c] * dv);
            __half2* p = (__half2*)&hs[(size_t)node * F_H + fi * 4];
            p[0] = h0; p[1] = h1;
        }
    }
}

// ---------------------------------------------------------------------------
// Aggregate L1 (LDS accumulator, src-window-ordered) + relu + wc2 projection:
// one block per dst bucket; acc[196][64] f32 in LDS; edges sorted by src so
// all blocks sweep the same hs window -> cross-block L2 reuse.
// ---------------------------------------------------------------------------
#define AG_T 512
#define AG_W (AG_T / 64)     // 8 waves
__global__ __launch_bounds__(AG_T) void k_agg1(const int* __restrict__ bbase,
                                               const int* __restrict__ packS,
                                               const __half* __restrict__ hs,
                                               const float* __restrict__ dinv,
                                               const float* __restrict__ b1,
                                               const float* __restrict__ wc2,
                                               float* __restrict__ q) {
    __shared__ float acc[NPB * F_H];   // 50176 B -> 3 blocks/CU
    int b = blockIdx.x;
    int node0 = b * NPB;
    int nloc = N_NODES - node0; if (nloc > NPB) nloc = NPB; if (nloc < 0) nloc = 0;
    int t = threadIdx.x, lane = t & 63, wv = t >> 6;
    const int SMASK = (1 << SRC_BITS) - 1;

    // self-loop init: acc[i][f] = hs[node0+i][f]
    for (int i = wv; i < nloc; i += AG_W)
        acc[i * F_H + lane] = __half2float(hs[(size_t)(node0 + i) * F_H + lane]);
    __syncthreads();

    int beg = bbase[b], len = bbase[b + 1] - beg;
    // groups of 8 consecutive edges per wave, waves interleaved (window-synced)
    for (int blk = wv; blk * 8 < len; blk += AG_W) {
        int e0 = beg + blk * 8;
        int n8 = len - blk * 8; if (n8 > 8) n8 = 8;
        if (n8 == 8) {
            int pk0 = packS[e0 + 0], pk1 = packS[e0 + 1];
            int pk2 = packS[e0 + 2], pk3 = packS[e0 + 3];
            int pk4 = packS[e0 + 4], pk5 = packS[e0 + 5];
            int pk6 = packS[e0 + 6], pk7 = packS[e0 + 7];
            float v0 = __half2float(hs[(size_t)(pk0 & SMASK) * F_H + lane]);
            float v1 = __half2float(hs[(size_t)(pk1 & SMASK) * F_H + lane]);
            float v2 = __half2float(hs[(size_t)(pk2 & SMASK) * F_H + lane]);
            float v3 = __half2float(hs[(size_t)(pk3 & SMASK) * F_H + lane]);
            float v4 = __half2float(hs[(size_t)(pk4 & SMASK) * F_H + lane]);
            float v5 = __half2float(hs[(size_t)(pk5 & SMASK) * F_H + lane]);
            float v6 = __half2float(hs[(size_t)(pk6 & SMASK) * F_H + lane]);
            float v7 = __half2float(hs[(size_t)(pk7 & SMASK) * F_H + lane]);
            atomicAdd(&acc[(pk0 >> SRC_BITS) * F_H + lane], v0);
            atomicAdd(&acc[(pk1 >> SRC_BITS) * F_H + lane], v1);
            atomicAdd(&acc[(pk2 >> SRC_BITS) * F_H + lane], v2);
            atomicAdd(&acc[(pk3 >> SRC_BITS) * F_H + lane], v3);
            atomicAdd(&acc[(pk4 >> SRC_BITS) * F_H + lane], v4);
            atomicAdd(&acc[(pk5 >> SRC_BITS) * F_H + lane], v5);
            atomicAdd(&acc[(pk6 >> SRC_BITS) * F_H + lane], v6);
            atomicAdd(&acc[(pk7 >> SRC_BITS) * F_H + lane], v7);
        } else {
            for (int j = 0; j < n8; j++) {
                int pk = packS[e0 + j];
                float v = __half2float(hs[(size_t)(pk & SMASK) * F_H + lane]);
                atomicAdd(&acc[(pk >> SRC_BITS) * F_H + lane], v);
            }
        }
    }
    __syncthreads();
    // epilogue: z = relu(dinv*acc + b1); q = dinv * dot(z, wc2)
    float bl = b1[lane], wl = wc2[lane];
    for (int i = wv; i < nloc; i += AG_W) {
        float dv = dinv[node0 + i];
        float z = fmaxf(dv * acc[i * F_H + lane] + bl, 0.0f);
        float p = z * wl;
#pragma unroll
        for (int off = 32; off > 0; off >>= 1)
            p += __shfl_xor(p, off, 64);
        if (lane == 0) q[node0 + i] = dv * p;
    }
}

// ---------------------------------------------------------------------------
// Final (collapsed layer2+head): out[d] = dinv[d]*(q[d] + sum q[src]) + c0
// one block per bucket, scalar LDS accumulator; q (400 KB) is L2-resident
// ---------------------------------------------------------------------------
#define FN_T 256
__global__ __launch_bounds__(FN_T) void k_final(const int* __restrict__ bbase,
                                                const int* __restrict__ packS,
                                                const float* __restrict__ q,
                                                const float* __restrict__ dinv,
                                                const float* __restrict__ c0,
                                                float* __restrict__ out) {
    __shared__ float sacc[NPB];
    int b = blockIdx.x;
    int node0 = b * NPB;
    int nloc = N_NODES - node0; if (nloc > NPB) nloc = NPB; if (nloc < 0) nloc = 0;
    int t = threadIdx.x;
    const int SMASK = (1 << SRC_BITS) - 1;
    for (int i = t; i < nloc; i += FN_T) sacc[i] = q[node0 + i];
    __syncthreads();
    int beg = bbase[b], len = bbase[b + 1] - beg;
    for (int i = t; i < len; i += FN_T) {
        int pk = packS[beg + i];
        atomicAdd(&sacc[pk >> SRC_BITS], q[pk & SMASK]);
    }
    __syncthreads();
    for (int i = t; i < nloc; i += FN_T)
        out[node0 + i] = dinv[node0 + i] * sacc[i] + c0[0];
}

// ---------------------------------------------------------------------------
extern "C" void kernel_launch(void* const* d_in, const int* in_sizes, int n_in,
                              void* d_out, int out_size, void* d_ws, size_t ws_size,
                              hipStream_t stream) {
    const float* x  = (const float*)d_in[0];
    const int*   ei = (const int*)d_in[1];
    const int*   src = ei;
    const int*   dst = ei + N_EDGES;
    const float* W1 = (const float*)d_in[2];
    const float* b1 = (const float*)d_in[3];
    const float* W2 = (const float*)d_in[4];
    const float* b2 = (const float*)d_in[5];
    const float* Wc = (const float*)d_in[6];
    const float* bc = (const float*)d_in[7];
    float* out = (float*)d_out;

    char* w = (char*)d_ws;
    int*    bcount  = (int*)w;    w += NBUCK * 4;
    int*    bbase   = (int*)w;    w += (NBUCK + 1) * 4;
    int*    bcur    = (int*)w;    w += NBUCK * 4;
    float*  wc2     = (float*)w;  w += 64 * 4;
    float*  c0      = (float*)w;  w += 4 * 4;
    float*  dinv    = (float*)w;  w += (size_t)N_NODES * 4;
    float*  q       = (float*)w;  w += (size_t)N_NODES * 4;
    int*    packS   = (int*)w;    w += (size_t)N_EDGES * 4;        // src-sorted per bucket
    __half* bufA    = (__half*)w; w += (size_t)N_NODES * F_H * 2;  // hs1 (12.8 MB)
    int*    packT   = (int*)w;    w += (size_t)N_EDGES * 4;        // partA intermediate

    const int NB_BH = (int)(((long long)N_EDGES + BH_C - 1) / BH_C);  // 196
    const int NB_PA = (int)(((long long)N_EDGES + PA_C - 1) / PA_C);  // 782
    const int NB_G  = (N_NODES + NTB - 1) / NTB;                      // 782

    hipMemsetAsync(bcount, 0, NBUCK * 4, stream);
    k_bhist<<<NB_BH, BH_T, 0, stream>>>(dst, bcount);
    k_bscan<<<1, NBUCK, 0, stream>>>(bcount, bbase, bcur);
    k_wc2  <<<1, 64, 0, stream>>>(W2, Wc, b2, bc, wc2, c0);
    k_partA<<<NB_PA, PA_T, 0, stream>>>(src, dst, bcur, packT);
    k_partB<<<NBUCK, PB_T, 0, stream>>>(bbase, packT, dinv, packS);

    // layer 1: gemm -> hs fp16; bucketed LDS aggregation + relu + projection -> q
    k_gemm1<<<NB_G, GT, 0, stream>>>(x, W1, dinv, bufA);
    k_agg1<<<NBUCK, AG_T, 0, stream>>>(bbase, packS, bufA, dinv, b1, wc2, q);

    // collapsed layer 2 + head: scalar bucketed aggregation over q
    k_final<<<NBUCK, FN_T, 0, stream>>>(bbase, packS, q, dinv, c0, out);
}

// Round 9
// 317.173 us; speedup vs baseline: 4.0475x; 4.0475x over previous
//
#include <hip/hip_runtime.h>
#include <hip/hip_bf16.h>
#include <hip/hip_fp16.h>

#define N_NODES 100000
#define N_EDGES 3200000
#define F_IN    128
#define F_H     64

#define NBUCK 256
#define NPB   391            // ceil(N_NODES / NBUCK); last bucket short
#define SRC_BITS 17          // N_NODES < 2^17; pack = (dstLocal<<17)|src

// ---------------------------------------------------------------------------
// Bucket-level histogram: 256 bins, LDS-aggregated (50K global atomics total)
// ---------------------------------------------------------------------------
#define BH_T 256
#define BH_C 16384           // edges per block -> 196 blocks
__global__ __launch_bounds__(BH_T) void k_bhist(const int* __restrict__ dst,
                                                int* __restrict__ bcount) {
    __shared__ int lc[NBUCK];
    int t = threadIdx.x;
    lc[t] = 0;
    __syncthreads();
    long long e0 = (long long)blockIdx.x * BH_C;
    long long e1 = e0 + BH_C; if (e1 > N_EDGES) e1 = N_EDGES;
    for (long long e = e0 + t; e < e1; e += BH_T)
        atomicAdd(&lc[dst[e] / NPB], 1);
    __syncthreads();
    int c = lc[t];
    if (c) atomicAdd(&bcount[t], c);
}

// ---------------------------------------------------------------------------
// Scan of 256 bucket counts -> bucket bases + partA cursors; row_ptr[N]=E
// ---------------------------------------------------------------------------
__global__ __launch_bounds__(NBUCK) void k_bscan(const int* __restrict__ bcount,
                                                 int* __restrict__ bbase,
                                                 int* __restrict__ bcur,
                                                 int* __restrict__ row_ptr) {
    __shared__ int s[NBUCK];
    int t = threadIdx.x;
    int c = bcount[t];
    s[t] = c;
    __syncthreads();
    for (int off = 1; off < NBUCK; off <<= 1) {
        int v = (t >= off) ? s[t - off] : 0;
        __syncthreads();
        s[t] += v;
        __syncthreads();
    }
    int ex = s[t] - c;
    bbase[t] = ex;
    bcur[t]  = ex;
    if (t == NBUCK - 1) {
        bbase[NBUCK] = s[t];             // = N_EDGES
        row_ptr[N_NODES] = s[t];
    }
}

// ---------------------------------------------------------------------------
// wc2 = W2^T Wc (64-vector), c0 = Wc.b2 + bc  — collapses layer2+head
// ---------------------------------------------------------------------------
__global__ __launch_bounds__(64) void k_wc2(const float* __restrict__ W2,
                                            const float* __restrict__ Wc,
                                            const float* __restrict__ b2,
                                            const float* __restrict__ bc,
                                            float* __restrict__ wc2,
                                            float* __restrict__ c0) {
    int k = threadIdx.x;
    float s = 0.0f;
#pragma unroll 8
    for (int f = 0; f < F_H; f++) s += Wc[f] * W2[f * F_H + k];
    wc2[k] = s;
    float p = Wc[k] * b2[k];
#pragma unroll
    for (int off = 32; off > 0; off >>= 1) p += __shfl_xor(p, off, 64);
    if (k == 0) c0[0] = p + bc[0];
}

// ---------------------------------------------------------------------------
// Pass A: partition edges into NBUCK dst-range buckets; emit packed
// (dstLocal<<17)|src words (LDS-staged, coalesced out)
// ---------------------------------------------------------------------------
#define PA_T   256
#define PA_C   4096
#define PA_PER (PA_C / PA_T)   // 16
__global__ __launch_bounds__(PA_T) void k_partA(const int* __restrict__ src,
                                                const int* __restrict__ dst,
                                                int* __restrict__ bucket_cursor,
                                                int* __restrict__ packT) {
    __shared__ int lcount[NBUCK];
    __shared__ int lstart[NBUCK];
    __shared__ int loffs[NBUCK];
    __shared__ int lbase[NBUCK];
    __shared__ int s_pack[PA_C];
    __shared__ unsigned char s_bkt[PA_C];
    __shared__ int ltot;
    int t = threadIdx.x;
    long long e0 = (long long)blockIdx.x * PA_C;
    if (t < NBUCK) lcount[t] = 0;
    __syncthreads();
    int ep[PA_PER];
    short eb[PA_PER];
#pragma unroll
    for (int i = 0; i < PA_PER; i++) {
        long long e = e0 + i * PA_T + t;
        if (e < N_EDGES) {
            int es = src[e], ed = dst[e];
            int b = ed / NPB;
            eb[i] = (short)b;
            ep[i] = ((ed - b * NPB) << SRC_BITS) | es;
            atomicAdd(&lcount[b], 1);
        } else eb[i] = -1;
    }
    __syncthreads();
    // exclusive scan of lcount (256) by wave 0: 4 serial/lane + shfl scan
    if (t < 64) {
        int base = t * 4;
        int c0 = lcount[base], c1 = lcount[base + 1], c2 = lcount[base + 2], c3 = lcount[base + 3];
        int ssum = c0 + c1 + c2 + c3;
        int sc = ssum;
#pragma unroll
        for (int off = 1; off < 64; off <<= 1) {
            int v = __shfl_up(sc, off, 64);
            if (t >= off) sc += v;
        }
        int ex = sc - ssum;
        lstart[base]     = ex;
        lstart[base + 1] = ex + c0;
        lstart[base + 2] = ex + c0 + c1;
        lstart[base + 3] = ex + c0 + c1 + c2;
        if (t == 63) ltot = sc;
    }
    __syncthreads();
    if (t < NBUCK) {
        loffs[t] = lstart[t];
        int c = lcount[t];
        lbase[t] = c ? atomicAdd(&bucket_cursor[t], c) : 0;
    }
    __syncthreads();
#pragma unroll
    for (int i = 0; i < PA_PER; i++) {
        if (eb[i] >= 0) {
            int idx = atomicAdd(&loffs[eb[i]], 1);
            s_pack[idx] = ep[i];
            s_bkt[idx] = (unsigned char)eb[i];
        }
    }
    __syncthreads();
    int tot = ltot;
    for (int i = t; i < tot; i += PA_T) {
        int b = s_bkt[i];
        int addr = lbase[b] + (i - lstart[b]);
        packT[addr] = s_pack[i];
    }
}

// ---------------------------------------------------------------------------
// Pass B: per-bucket LDS counting sort of packed words -> srcs[] segment,
// plus derives row_ptr[node] and dinv[node] from the local histogram.
// ---------------------------------------------------------------------------
#define PB_T   1024
#define PB_CAP 16384
__global__ __launch_bounds__(PB_T) void k_partB(const int* __restrict__ bbase,
                                                const int* __restrict__ packT,
                                                int* __restrict__ row_ptr,
                                                float* __restrict__ dinv,
                                                int* __restrict__ srcs) {
    __shared__ int lhist[NPB];
    __shared__ int lcur[NPB];
    __shared__ int s_out[PB_CAP];
    int b = blockIdx.x;
    int node0 = b * NPB;
    int node1 = min(node0 + NPB, N_NODES);
    int nloc = node1 - node0;
    int beg = bbase[b];
    int end = bbase[b + 1];
    int len = end - beg;
    int t = threadIdx.x;
    const int SMASK = (1 << SRC_BITS) - 1;

    for (int i = t; i < NPB; i += PB_T) lhist[i] = 0;
    __syncthreads();
    for (int i = t; i < len; i += PB_T)
        atomicAdd(&lhist[packT[beg + i] >> SRC_BITS], 1);
    __syncthreads();
    if (t < 64) {   // exclusive scan of 391 counters: 7/lane + shfl
        int base = t * 7;
        int c[7]; int ssum = 0;
#pragma unroll
        for (int j = 0; j < 7; j++) {
            int idx = base + j;
            c[j] = (idx < NPB) ? lhist[idx] : 0;
            ssum += c[j];
        }
        int sc = ssum;
#pragma unroll
        for (int off = 1; off < 64; off <<= 1) {
            int v = __shfl_up(sc, off, 64);
            if (t >= off) sc += v;
        }
        int ex = sc - ssum;
#pragma unroll
        for (int j = 0; j < 7; j++) {
            int idx = base + j;
            if (idx < NPB) lcur[idx] = ex;
            ex += c[j];
        }
    }
    __syncthreads();
    // derive row_ptr / dinv from local exclusive prefix (before lcur mutates)
    for (int i = t; i < nloc; i += PB_T) {
        row_ptr[node0 + i] = beg + lcur[i];
        dinv[node0 + i] = rsqrtf((float)(lhist[i] + 1));
    }
    __syncthreads();
    if (len <= PB_CAP) {
        for (int i = t; i < len; i += PB_T) {
            int pk = packT[beg + i];
            int idx = atomicAdd(&lcur[pk >> SRC_BITS], 1);
            s_out[idx] = pk & SMASK;
        }
        __syncthreads();
        for (int i = t; i < len; i += PB_T)
            srcs[beg + i] = s_out[i];
    } else {    // statistically never (34 sigma): direct global scatter
        for (int i = t; i < len; i += PB_T) {
            int pk = packT[beg + i];
            int idx = atomicAdd(&lcur[pk >> SRC_BITS], 1);
            srcs[beg + idx] = pk & SMASK;
        }
    }
}

// ---------------------------------------------------------------------------
// Layer-1 GEMM: hs16 = fp16( (x @ W1^T) * dinv )
// Register-tiled: block = 256 thr (4 waves), 128 nodes/block.
// ---------------------------------------------------------------------------
#define GT   256
#define NTB  128     // nodes per block
#define KT   64      // k-tile (2 passes for F_IN=128)
#define WTS  68      // wT stride (words)

__global__ __launch_bounds__(GT) void k_gemm1(const float* __restrict__ x,
                                              const float* __restrict__ W1,
                                              const float* __restrict__ dinv,
                                              __half* __restrict__ hs) {
    __shared__ float wT[KT * WTS];     // 17.4 KB
    __shared__ float xT[KT * NTB];     // 32 KB
    int t = threadIdx.x;
    int node0 = blockIdx.x * NTB;
    int lane = t & 63, wv = t >> 6;
    int fi = lane & 15, ni = lane >> 4;
    int n0 = wv * 32 + ni * 8;

    float acc[4][8];
#pragma unroll
    for (int r = 0; r < 4; r++)
#pragma unroll
        for (int c = 0; c < 8; c++) acc[r][c] = 0.0f;

    for (int p = 0; p < 2; p++) {
        int k0 = p * KT;
        if (p) __syncthreads();
        {
            int f = t & 63, kq = t >> 6;
            const float4* wp = (const float4*)&W1[(size_t)f * F_IN + k0 + kq * 16];
#pragma unroll
            for (int j = 0; j < 4; j++) {
                float4 v = wp[j];
                int kl = kq * 16 + 4 * j;
                wT[(kl + 0) * WTS + f] = v.x;
                wT[(kl + 1) * WTS + f] = v.y;
                wT[(kl + 2) * WTS + f] = v.z;
                wT[(kl + 3) * WTS + f] = v.w;
            }
        }
        {
            int n = t & 127, half = t >> 7;
            int node = node0 + n;
#pragma unroll
            for (int j = 0; j < 8; j++) {
                int ku = half * 8 + j;
                float4 v = make_float4(0.f, 0.f, 0.f, 0.f);
                if (node < N_NODES)
                    v = *(const float4*)&x[(size_t)node * F_IN + k0 + 4 * ku];
                int kl = 4 * ku;
                xT[(kl + 0) * NTB + n] = v.x;
                xT[(kl + 1) * NTB + n] = v.y;
                xT[(kl + 2) * NTB + n] = v.z;
                xT[(kl + 3) * NTB + n] = v.w;
            }
        }
        __syncthreads();
#pragma unroll 8
        for (int k = 0; k < KT; k++) {
            float4 wf = *(const float4*)&wT[k * WTS + fi * 4];
            float4 xa = *(const float4*)&xT[k * NTB + n0];
            float4 xb = *(const float4*)&xT[k * NTB + n0 + 4];
            float wr[4] = {wf.x, wf.y, wf.z, wf.w};
            float xv[8] = {xa.x, xa.y, xa.z, xa.w, xb.x, xb.y, xb.z, xb.w};
#pragma unroll
            for (int r = 0; r < 4; r++)
#pragma unroll
                for (int c = 0; c < 8; c++) acc[r][c] += wr[r] * xv[c];
        }
    }
#pragma unroll
    for (int c = 0; c < 8; c++) {
        int node = node0 + n0 + c;
        if (node < N_NODES) {
            float dv = dinv[node];
            __half2 h0 = __floats2half2_rn(acc[0][c] * dv, acc[1][c] * dv);
            __half2 h1 = __floats2half2_rn(acc[2][c] * dv, acc[3][c] * dv);
            __half2* p = (__half2*)&hs[(size_t)node * F_H + fi * 4];
            p[0] = h0; p[1] = h1;
        }
    }
}

// ---------------------------------------------------------------------------
// Aggregate L1 + relu + wc2 projection. Pair-gather: one wave per node;
// lanes 0-31 handle even edges, lanes 32-63 odd edges; each lane loads one
// __half2 (2 features). 8 dword gathers in flight = 16 edges/iteration.
// ---------------------------------------------------------------------------
__global__ void k_agg1q(const int* __restrict__ row_ptr, const int* __restrict__ srcs,
                        const __half* __restrict__ hs, const float* __restrict__ dinv,
                        const float* __restrict__ b1, const float* __restrict__ wc2,
                        float* __restrict__ q) {
    unsigned tid = blockIdx.x * blockDim.x + threadIdx.x;
    unsigned node = tid >> 6;
    int lane = tid & 63;
    if (node >= N_NODES) return;
    int up = lane >> 5;            // 0 = even edges, 1 = odd edges
    int fp = lane & 31;            // feature pair: features 2fp, 2fp+1
    const __half2* hs2 = (const __half2*)hs;

    int beg = row_ptr[node], end = row_ptr[node + 1];
    float2 acc = make_float2(0.0f, 0.0f);
    if (up == 0) {                 // self-loop on lower half only
        float2 s = __half22float2(hs2[(size_t)node * 32 + fp]);
        acc.x = s.x; acc.y = s.y;
    }
    int j = beg;
    for (; j + 16 <= end; j += 16) {
        int s[16];
#pragma unroll
        for (int u = 0; u < 16; u++) s[u] = srcs[j + u];
#pragma unroll
        for (int u = 0; u < 8; u++) {
            int sel = up ? s[2 * u + 1] : s[2 * u];
            float2 v = __half22float2(hs2[(size_t)sel * 32 + fp]);
            acc.x += v.x; acc.y += v.y;
        }
    }
    for (; j + 2 <= end; j += 2) {
        int sel = up ? srcs[j + 1] : srcs[j];
        float2 v = __half22float2(hs2[(size_t)sel * 32 + fp]);
        acc.x += v.x; acc.y += v.y;
    }
    if (j < end && up == 0) {      // odd leftover edge: lower half only
        float2 v = __half22float2(hs2[(size_t)srcs[j] * 32 + fp]);
        acc.x += v.x; acc.y += v.y;
    }
    // combine halves (both halves then hold the full sum)
    acc.x += __shfl_xor(acc.x, 32, 64);
    acc.y += __shfl_xor(acc.y, 32, 64);
    // epilogue: z = relu(dinv*acc + b1); q = dinv * dot(z, wc2)
    float dv = dinv[node];
    float2 bb = *(const float2*)&b1[2 * fp];
    float2 ww = *(const float2*)&wc2[2 * fp];
    float z0 = fmaxf(dv * acc.x + bb.x, 0.0f);
    float z1 = fmaxf(dv * acc.y + bb.y, 0.0f);
    float p = z0 * ww.x + z1 * ww.y;
#pragma unroll
    for (int off = 16; off > 0; off >>= 1)
        p += __shfl_xor(p, off, 64);
    if (lane == 0) q[node] = dv * p;
}

// ---------------------------------------------------------------------------
// Final: out[d] = dinv[d] * (q[d] + sum_{s->d} q[s]) + c0
// one thread per node; q (400 KB) is L2-resident
// ---------------------------------------------------------------------------
__global__ void k_final(const int* __restrict__ row_ptr, const int* __restrict__ srcs,
                        const float* __restrict__ q, const float* __restrict__ dinv,
                        const float* __restrict__ c0, float* __restrict__ out) {
    int node = blockIdx.x * blockDim.x + threadIdx.x;
    if (node >= N_NODES) return;
    int beg = row_ptr[node], end = row_ptr[node + 1];
    float acc = q[node];
    int j = beg;
    for (; j + 4 <= end; j += 4) {
        int s0 = srcs[j], s1 = srcs[j + 1], s2 = srcs[j + 2], s3 = srcs[j + 3];
        float a0 = q[s0], a1 = q[s1], a2 = q[s2], a3 = q[s3];
        acc += (a0 + a1) + (a2 + a3);
    }
    for (; j < end; j++) acc += q[srcs[j]];
    out[node] = dinv[node] * acc + c0[0];
}

// ---------------------------------------------------------------------------
extern "C" void kernel_launch(void* const* d_in, const int* in_sizes, int n_in,
                              void* d_out, int out_size, void* d_ws, size_t ws_size,
                              hipStream_t stream) {
    const float* x  = (const float*)d_in[0];
    const int*   ei = (const int*)d_in[1];
    const int*   src = ei;
    const int*   dst = ei + N_EDGES;
    const float* W1 = (const float*)d_in[2];
    const float* b1 = (const float*)d_in[3];
    const float* W2 = (const float*)d_in[4];
    const float* b2 = (const float*)d_in[5];
    const float* Wc = (const float*)d_in[6];
    const float* bc = (const float*)d_in[7];
    float* out = (float*)d_out;

    char* w = (char*)d_ws;
    int*    bcount  = (int*)w;    w += NBUCK * 4;
    int*    bbase   = (int*)w;    w += (NBUCK + 1) * 4;
    int*    bcur    = (int*)w;    w += NBUCK * 4;
    float*  wc2     = (float*)w;  w += 64 * 4;
    float*  c0      = (float*)w;  w += 4 * 4;
    int*    row_ptr = (int*)w;    w += ((size_t)N_NODES + 4) * 4;
    float*  dinv    = (float*)w;  w += (size_t)N_NODES * 4;
    float*  q       = (float*)w;  w += (size_t)N_NODES * 4;
    int*    srcs    = (int*)w;    w += (size_t)N_EDGES * 4;
    __half* bufA    = (__half*)w; w += (size_t)N_NODES * F_H * 2;  // hs1 (12.8 MB)
    int*    packT   = (int*)w;    w += (size_t)N_EDGES * 4;        // sort intermediate

    const int TB = 256;
    const int NB_BH = (int)(((long long)N_EDGES + BH_C - 1) / BH_C);  // 196
    const int NB_PA = (int)(((long long)N_EDGES + PA_C - 1) / PA_C);  // 782
    const int NB_G  = (N_NODES + NTB - 1) / NTB;                      // 782

    hipMemsetAsync(bcount, 0, NBUCK * 4, stream);
    k_bhist<<<NB_BH, BH_T, 0, stream>>>(dst, bcount);
    k_bscan<<<1, NBUCK, 0, stream>>>(bcount, bbase, bcur, row_ptr);
    k_wc2  <<<1, 64, 0, stream>>>(W2, Wc, b2, bc, wc2, c0);
    k_partA<<<NB_PA, PA_T, 0, stream>>>(src, dst, bcur, packT);
    k_partB<<<NBUCK, PB_T, 0, stream>>>(bbase, packT, row_ptr, dinv, srcs);

    // layer 1: gemm -> hs fp16; aggregate+relu+project -> q
    k_gemm1<<<NB_G, GT, 0, stream>>>(x, W1, dinv, bufA);
    k_agg1q<<<((unsigned)N_NODES * 64 + TB - 1) / TB, TB, 0, stream>>>(row_ptr, srcs, bufA, dinv, b1, wc2, q);

    // collapsed layer 2 + head: scalar gather over q
    k_final<<<(N_NODES + TB - 1) / TB, TB, 0, stream>>>(row_ptr, srcs, q, dinv, c0, out);
}